// Round 7
// baseline (525.672 us; speedup 1.0000x reference)
//
#include <hip/hip_runtime.h>
#include <hip/hip_bf16.h>
#include <math.h>

#define NNODE 4096
#define FDIM  256
#define NHEAD 4
#define MAXE  128
#define SLOPE 0.2f

// -------- adj layout detector: byte-bools vs int32 0/1 ----------------------
// Reads byte offsets i*4097, i in [1,1024): max 4.19 MB -> safe under both
// layouts (byte buffer = 16 MB, int32 buffer = 64 MB).
// Byte layout: these are diagonal self-loops -> all 1 -> sum = 1023.
// Int32 layout: byte 1..3 of a 0/1 word is always 0; only i%4==0 hits a low
// byte of some word (~1% ones) -> sum ~ 3. Threshold 512.
__global__ __launch_bounds__(256) void detect_adj_k(const unsigned char* __restrict__ adj,
                                                    int* __restrict__ flag) {
    int tid = threadIdx.x;
    int s = 0;
    for (int i = 1 + tid; i < 1024; i += 256) s += adj[(size_t)i * 4097];
    __shared__ int sh;
    if (tid == 0) sh = 0;
    __syncthreads();
    atomicAdd(&sh, s);
    __syncthreads();
    if (tid == 0) *flag = (sh > 512) ? 1 : 0;   // 1 = byte layout, 0 = int32 layout
}

// ---------------- edge list build, dual-layout ------------------------------
__global__ __launch_bounds__(256) void build_edges_k(const unsigned char* __restrict__ adj,
                                                     const int* __restrict__ flag,
                                                     int* __restrict__ cols,
                                                     int* __restrict__ cnt) {
    int n = blockIdx.x;
    __shared__ int c;
    if (threadIdx.x == 0) c = 0;
    __syncthreads();
    if (*flag) {
        // 1-byte bools, row-major [N,N]
        const uint32_t* row = (const uint32_t*)(adj + (size_t)n * NNODE);
        for (int w = threadIdx.x; w < NNODE / 4; w += 256) {
            uint32_t v = row[w];
            if (v) {
#pragma unroll
                for (int b = 0; b < 4; b++) {
                    if ((v >> (8 * b)) & 0xffu) {
                        int p = atomicAdd(&c, 1);
                        if (p < MAXE) cols[(size_t)n * MAXE + p] = w * 4 + b;
                    }
                }
            }
        }
    } else {
        // int32 0/1, row-major [N,N]
        const int4* row = (const int4*)((const int*)adj + (size_t)n * NNODE);
        for (int w = threadIdx.x; w < NNODE / 4; w += 256) {
            int4 v = row[w];
            if (v.x | v.y | v.z | v.w) {
                if (v.x) { int p = atomicAdd(&c, 1); if (p < MAXE) cols[(size_t)n * MAXE + p] = w * 4 + 0; }
                if (v.y) { int p = atomicAdd(&c, 1); if (p < MAXE) cols[(size_t)n * MAXE + p] = w * 4 + 1; }
                if (v.z) { int p = atomicAdd(&c, 1); if (p < MAXE) cols[(size_t)n * MAXE + p] = w * 4 + 2; }
                if (v.w) { int p = atomicAdd(&c, 1); if (p < MAXE) cols[(size_t)n * MAXE + p] = w * 4 + 3; }
            }
        }
    }
    __syncthreads();
    if (threadIdx.x == 0) cnt[n] = (c < MAXE) ? c : MAXE;
}

// ---------------- attention logit vectors: f = h . a ------------------------
__global__ __launch_bounds__(256) void fvec_k(const float* __restrict__ h,
                                              const float* __restrict__ a,
                                              float* __restrict__ fsrc,
                                              float* __restrict__ fdst) {
    int wid  = blockIdx.x * 4 + (threadIdx.x >> 6);   // (hd*NNODE + n)
    int lane = threadIdx.x & 63;
    int hd   = wid >> 12;
    const float* hrow = h + (size_t)wid * FDIM;
    const float* av   = a + hd * FDIM * 2;
    float s0 = 0.f, s1 = 0.f;
#pragma unroll
    for (int it = 0; it < 4; it++) {
        int g = lane + it * 64;
        float v = hrow[g];
        s0 += v * av[2 * g];
        s1 += v * av[2 * g + 1];
    }
    for (int off = 32; off; off >>= 1) {
        s0 += __shfl_down(s0, off);
        s1 += __shfl_down(s1, off);
    }
    if (lane == 0) { fsrc[wid] = s0; fdst[wid] = s1; }
}

// ------- fused: sparse edge softmax + aggregation + residual + ELU + mean ----
// One block per node n; loops the 4 heads; no aggb intermediate.
__global__ __launch_bounds__(256) void agg_fused_k(const float* __restrict__ h,
                                                   const float* __restrict__ fsrc,
                                                   const float* __restrict__ fdst,
                                                   const int* __restrict__ cols,
                                                   const int* __restrict__ cnt,
                                                   const float* __restrict__ X,
                                                   float* __restrict__ Y) {
    int n   = blockIdx.x;
    int tid = threadIdx.x;
    __shared__ float ev[MAXE];
    __shared__ int   cls[MAXE];
    __shared__ float sinv_s;
    int c = cnt[n];
    if (tid < MAXE && tid < c) cls[tid] = cols[(size_t)n * MAXE + tid];
    float xv = X[(size_t)n * FDIM + tid];
    float smean = 0.f;
#pragma unroll
    for (int hd = 0; hd < NHEAD; hd++) {
        __syncthreads();                       // previous head's ev readers done
        if (tid < MAXE) {
            float e;
            if (tid < c) {
                float z = fsrc[(hd << 12) + n] + fdst[(hd << 12) + cls[tid]];
                e = z > 0.f ? z : SLOPE * z;   // leaky_relu(f_src[n] + f_dst[m])
            } else {
                e = -1e30f;
            }
            ev[tid] = e;
        }
        __syncthreads();
        if (tid < 64) {
            float m0 = fmaxf(ev[tid], ev[tid + 64]);
            for (int off = 32; off; off >>= 1) m0 = fmaxf(m0, __shfl_down(m0, off));
            m0 = __shfl(m0, 0);
            float e0 = (tid      < c) ? expf(ev[tid]      - m0) : 0.f;
            float e1 = (tid + 64 < c) ? expf(ev[tid + 64] - m0) : 0.f;
            ev[tid] = e0; ev[tid + 64] = e1;
            float s = e0 + e1;
            for (int off = 32; off; off >>= 1) s += __shfl_down(s, off);
            if (tid == 0) sinv_s = 1.f / s;
        }
        __syncthreads();
        const float* hh = h + (size_t)hd * NNODE * FDIM;
        float inv = sinv_s;
        float acc = 0.f;
        for (int j = 0; j < c; j++) {
            acc += ev[j] * hh[(size_t)cls[j] * FDIM + tid];   // coalesced 1KB/edge gather
        }
        float v = acc * inv + xv;                              // residual
        smean += v > 0.f ? v : expm1f(v);                      // jax.nn.elu
    }
    Y[(size_t)n * FDIM + tid] = 0.25f * smean;                 // mean over heads
}

// ---------------- fp32 tiled GEMM: C = A @ B (batched over heads) -----------
__global__ __launch_bounds__(256) void gemm_k(const float* __restrict__ A,
                                              const float* __restrict__ B,
                                              float* __restrict__ C,
                                              int M, int Nc, int K,
                                              size_t bStrideZ, size_t cStrideZ) {
    __shared__ float As[32][132];
    __shared__ float Bs[32][132];
    const float* Bz = B + blockIdx.z * bStrideZ;
    float* Cz = C + blockIdx.z * cStrideZ;
    int tid = threadIdx.x;
    int tx = tid & 15, ty = tid >> 4;
    int row0 = blockIdx.x * 128, col0 = blockIdx.y * 128;
    float acc[8][8];
#pragma unroll
    for (int i = 0; i < 8; i++)
#pragma unroll
        for (int j = 0; j < 8; j++) acc[i][j] = 0.f;

    for (int k0 = 0; k0 < K; k0 += 32) {
        int r = tid >> 3, c4 = (tid & 7) << 2;
#pragma unroll
        for (int i = 0; i < 4; i++) {
            float4 v = *(const float4*)(A + (size_t)(row0 + r + i * 32) * K + (k0 + c4));
            As[c4 + 0][r + i * 32] = v.x;
            As[c4 + 1][r + i * 32] = v.y;
            As[c4 + 2][r + i * 32] = v.z;
            As[c4 + 3][r + i * 32] = v.w;
        }
        int br = tid >> 5, bc4 = (tid & 31) << 2;
#pragma unroll
        for (int i = 0; i < 4; i++) {
            float4 v = *(const float4*)(Bz + (size_t)(k0 + br + i * 8) * Nc + (col0 + bc4));
            *(float4*)&Bs[br + i * 8][bc4] = v;
        }
        __syncthreads();
#pragma unroll
        for (int k = 0; k < 32; k++) {
            float af[8], bf[8];
            *(float4*)&af[0] = *(const float4*)&As[k][ty * 8];
            *(float4*)&af[4] = *(const float4*)&As[k][ty * 8 + 4];
            *(float4*)&bf[0] = *(const float4*)&Bs[k][tx * 8];
            *(float4*)&bf[4] = *(const float4*)&Bs[k][tx * 8 + 4];
#pragma unroll
            for (int i = 0; i < 8; i++)
#pragma unroll
                for (int j = 0; j < 8; j++)
                    acc[i][j] = fmaf(af[i], bf[j], acc[i][j]);
        }
        __syncthreads();
    }
#pragma unroll
    for (int i = 0; i < 8; i++) {
        float4 v0 = make_float4(acc[i][0], acc[i][1], acc[i][2], acc[i][3]);
        float4 v1 = make_float4(acc[i][4], acc[i][5], acc[i][6], acc[i][7]);
        float* cp = Cz + (size_t)(row0 + ty * 8 + i) * Nc + col0 + tx * 8;
        *(float4*)cp = v0;
        *(float4*)(cp + 4) = v1;
    }
}

// ---------------- symmetric rank-k: C = Y @ Y^T, lower tiles + mirror -------
// Bit-exact: mirrored element is the same dot product in the same k-order.
__global__ __launch_bounds__(256) void syrk_k(const float* __restrict__ Y,
                                              float* __restrict__ C) {
    int bx = blockIdx.x, by = blockIdx.y;
    if (bx < by) return;
    __shared__ float As[32][132];
    __shared__ float Bs[32][132];
    int tid = threadIdx.x;
    int tx = tid & 15, ty = tid >> 4;
    int row0 = bx * 128, col0 = by * 128;
    const int K = FDIM, Nc = NNODE;
    float acc[8][8];
#pragma unroll
    for (int i = 0; i < 8; i++)
#pragma unroll
        for (int j = 0; j < 8; j++) acc[i][j] = 0.f;

    for (int k0 = 0; k0 < K; k0 += 32) {
        int r = tid >> 3, c4 = (tid & 7) << 2;
#pragma unroll
        for (int i = 0; i < 4; i++) {
            float4 v = *(const float4*)(Y + (size_t)(row0 + r + i * 32) * K + (k0 + c4));
            As[c4 + 0][r + i * 32] = v.x;
            As[c4 + 1][r + i * 32] = v.y;
            As[c4 + 2][r + i * 32] = v.z;
            As[c4 + 3][r + i * 32] = v.w;
        }
#pragma unroll
        for (int i = 0; i < 4; i++) {
            float4 v = *(const float4*)(Y + (size_t)(col0 + r + i * 32) * K + (k0 + c4));
            Bs[c4 + 0][r + i * 32] = v.x;
            Bs[c4 + 1][r + i * 32] = v.y;
            Bs[c4 + 2][r + i * 32] = v.z;
            Bs[c4 + 3][r + i * 32] = v.w;
        }
        __syncthreads();
#pragma unroll
        for (int k = 0; k < 32; k++) {
            float af[8], bf[8];
            *(float4*)&af[0] = *(const float4*)&As[k][ty * 8];
            *(float4*)&af[4] = *(const float4*)&As[k][ty * 8 + 4];
            *(float4*)&bf[0] = *(const float4*)&Bs[k][tx * 8];
            *(float4*)&bf[4] = *(const float4*)&Bs[k][tx * 8 + 4];
#pragma unroll
            for (int i = 0; i < 8; i++)
#pragma unroll
                for (int j = 0; j < 8; j++)
                    acc[i][j] = fmaf(af[i], bf[j], acc[i][j]);
        }
        __syncthreads();
    }
#pragma unroll
    for (int i = 0; i < 8; i++) {
        float4 v0 = make_float4(acc[i][0], acc[i][1], acc[i][2], acc[i][3]);
        float4 v1 = make_float4(acc[i][4], acc[i][5], acc[i][6], acc[i][7]);
        float* cp = C + (size_t)(row0 + ty * 8 + i) * Nc + col0 + tx * 8;
        *(float4*)cp = v0;
        *(float4*)(cp + 4) = v1;
    }
    if (bx != by) {
#pragma unroll
        for (int j = 0; j < 8; j++) {
            float4 v0 = make_float4(acc[0][j], acc[1][j], acc[2][j], acc[3][j]);
            float4 v1 = make_float4(acc[4][j], acc[5][j], acc[6][j], acc[7][j]);
            float* cp = C + (size_t)(col0 + tx * 8 + j) * Nc + row0 + ty * 8;
            *(float4*)cp = v0;
            *(float4*)(cp + 4) = v1;
        }
    }
}

extern "C" void kernel_launch(void* const* d_in, const int* in_sizes, int n_in,
                              void* d_out, int out_size, void* d_ws, size_t ws_size,
                              hipStream_t stream) {
    const float*         x   = (const float*)d_in[0];
    const unsigned char* adj = (const unsigned char*)d_in[1];   // layout auto-detected
    const float*         W   = (const float*)d_in[2];
    const float*         a   = (const float*)d_in[3];
    float*               out = (float*)d_out;

    // h lives in d_out's first 16 MB (d_out = 64 MB, fully overwritten by syrk
    // at the end; all h reads are stream-ordered before syrk's writes).
    float* h    = (float*)d_out;                                 // [H,N,F] 16 MB
    // d_ws usage ~10.6 MB (defensive vs unknown ws_size).
    float* bufA = (float*)d_ws;                                  // [N,F] 4 MB
    float* bufB = bufA + (size_t)NNODE * FDIM;                   // [N,F] 4 MB
    float* fsrc = bufB + (size_t)NNODE * FDIM;                   // [H,N]
    float* fdst = fsrc + (size_t)NHEAD * NNODE;                  // [H,N]
    int*   cols = (int*)(fdst + (size_t)NHEAD * NNODE);          // [N,128] 2 MB
    int*   cnt  = cols + (size_t)NNODE * MAXE;                   // [N]
    int*   flag = cnt + NNODE;                                   // [1]

    detect_adj_k<<<1, 256, 0, stream>>>(adj, flag);
    build_edges_k<<<NNODE, 256, 0, stream>>>(adj, flag, cols, cnt);

    auto layer = [&](const float* X, float* Y) {
        gemm_k<<<dim3(32, 2, NHEAD), 256, 0, stream>>>(
            X, W, h, NNODE, FDIM, FDIM, (size_t)FDIM * FDIM, (size_t)NNODE * FDIM);
        fvec_k<<<NHEAD * NNODE / 4, 256, 0, stream>>>(h, a, fsrc, fdst);
        agg_fused_k<<<NNODE, 256, 0, stream>>>(h, fsrc, fdst, cols, cnt, X, Y);
    };

    layer(x, bufA);
    layer(bufA, bufB);
    layer(bufB, bufA);

    // out = Y @ Y^T (symmetric: lower tiles computed, upper mirrored bit-exactly)
    syrk_k<<<dim3(32, 32, 1), 256, 0, stream>>>(bufA, out);
}

// Round 9
// 372.290 us; speedup vs baseline: 1.4120x; 1.4120x over previous
//
#include <hip/hip_runtime.h>
#include <hip/hip_bf16.h>
#include <math.h>

#define NNODE 4096
#define FDIM  256
#define NHEAD 4
#define MAXE  128
#define SLOPE 0.2f

typedef __attribute__((ext_vector_type(8))) short bf16x8;
typedef __attribute__((ext_vector_type(4))) float f32x4;

__device__ __forceinline__ float bf2f(ushort u) {
    union { unsigned int i; float f; } v; v.i = ((unsigned int)u) << 16; return v.f;
}
__device__ __forceinline__ ushort f2bf(float f) {   // RNE; inputs never NaN
    union { float f; unsigned int i; } v; v.f = f;
    unsigned int lsb = (v.i >> 16) & 1;
    return (ushort)((v.i + 0x7fffu + lsb) >> 16);
}

// -------- adj layout detector: byte-bools vs int32 0/1 (round-5, proven) ----
__global__ __launch_bounds__(256) void detect_adj_k(const unsigned char* __restrict__ adj,
                                                    int* __restrict__ flag) {
    int tid = threadIdx.x;
    int s = 0;
    for (int i = 1 + tid; i < 1024; i += 256) s += adj[(size_t)i * 4097];
    __shared__ int sh;
    if (tid == 0) sh = 0;
    __syncthreads();
    atomicAdd(&sh, s);
    __syncthreads();
    if (tid == 0) *flag = (sh > 512) ? 1 : 0;   // 1 = byte layout, 0 = int32 layout
}

// ---------------- edge list build, dual-layout ------------------------------
__global__ __launch_bounds__(256) void build_edges_k(const unsigned char* __restrict__ adj,
                                                     const int* __restrict__ flag,
                                                     int* __restrict__ cols,
                                                     int* __restrict__ cnt) {
    int n = blockIdx.x;
    __shared__ int c;
    if (threadIdx.x == 0) c = 0;
    __syncthreads();
    if (*flag) {
        const uint32_t* row = (const uint32_t*)(adj + (size_t)n * NNODE);
        for (int w = threadIdx.x; w < NNODE / 4; w += 256) {
            uint32_t v = row[w];
            if (v) {
#pragma unroll
                for (int b = 0; b < 4; b++) {
                    if ((v >> (8 * b)) & 0xffu) {
                        int p = atomicAdd(&c, 1);
                        if (p < MAXE) cols[(size_t)n * MAXE + p] = w * 4 + b;
                    }
                }
            }
        }
    } else {
        const int4* row = (const int4*)((const int*)adj + (size_t)n * NNODE);
        for (int w = threadIdx.x; w < NNODE / 4; w += 256) {
            int4 v = row[w];
            if (v.x | v.y | v.z | v.w) {
                if (v.x) { int p = atomicAdd(&c, 1); if (p < MAXE) cols[(size_t)n * MAXE + p] = w * 4 + 0; }
                if (v.y) { int p = atomicAdd(&c, 1); if (p < MAXE) cols[(size_t)n * MAXE + p] = w * 4 + 1; }
                if (v.z) { int p = atomicAdd(&c, 1); if (p < MAXE) cols[(size_t)n * MAXE + p] = w * 4 + 2; }
                if (v.w) { int p = atomicAdd(&c, 1); if (p < MAXE) cols[(size_t)n * MAXE + p] = w * 4 + 3; }
            }
        }
    }
    __syncthreads();
    if (threadIdx.x == 0) cnt[n] = (c < MAXE) ? c : MAXE;
}

// ---------------- casts -----------------------------------------------------
__global__ __launch_bounds__(256) void cast_x_k(const float* __restrict__ x,
                                                ushort* __restrict__ xbf) {
    int i = (blockIdx.x * 256 + threadIdx.x) * 4;
    float4 v = *(const float4*)&x[i];
    ushort4 o; o.x = f2bf(v.x); o.y = f2bf(v.y); o.z = f2bf(v.z); o.w = f2bf(v.w);
    *(ushort4*)&xbf[i] = o;
}
// WbfT[hd][n][k] = bf16(W[hd][k][n]) : removes the LDS transpose from proj GEMM
__global__ __launch_bounds__(256) void cast_wT_k(const float* __restrict__ W,
                                                 ushort* __restrict__ WbfT) {
    int b = blockIdx.x;              // hd*256 + n
    int hd = b >> 8, nn = b & 255;
    int k = threadIdx.x;
    WbfT[(size_t)b * 256 + k] = f2bf(W[(size_t)hd * 65536 + (size_t)k * 256 + nn]);
}

// ---------------- attention logit vectors: f = h . a (h is bf16) ------------
__global__ __launch_bounds__(256) void fvec_k(const ushort* __restrict__ h,
                                              const float* __restrict__ a,
                                              float* __restrict__ fsrc,
                                              float* __restrict__ fdst) {
    int wid  = blockIdx.x * 4 + (threadIdx.x >> 6);   // (hd*NNODE + n)
    int lane = threadIdx.x & 63;
    int hd   = wid >> 12;
    const ushort* hrow = h + (size_t)wid * FDIM;
    const float* av   = a + hd * FDIM * 2;
    float s0 = 0.f, s1 = 0.f;
#pragma unroll
    for (int it = 0; it < 4; it++) {
        int g = lane + it * 64;
        float v = bf2f(hrow[g]);
        s0 += v * av[2 * g];
        s1 += v * av[2 * g + 1];
    }
    for (int off = 32; off; off >>= 1) {
        s0 += __shfl_down(s0, off);
        s1 += __shfl_down(s1, off);
    }
    if (lane == 0) { fsrc[wid] = s0; fdst[wid] = s1; }
}

// ------- fused: sparse edge softmax + aggregation + residual + ELU + mean ----
// h bf16; writes Y (fp32, residual for next layer) and Ybf (bf16, GEMM input).
__global__ __launch_bounds__(256) void agg_fused_k(const ushort* __restrict__ h,
                                                   const float* __restrict__ fsrc,
                                                   const float* __restrict__ fdst,
                                                   const int* __restrict__ cols,
                                                   const int* __restrict__ cnt,
                                                   const float* __restrict__ X,
                                                   float* __restrict__ Y,
                                                   ushort* __restrict__ Ybf) {
    int n   = blockIdx.x;
    int tid = threadIdx.x;
    __shared__ float ev[MAXE];
    __shared__ int   cls[MAXE];
    __shared__ float sinv_s;
    int c = cnt[n];
    if (tid < MAXE && tid < c) cls[tid] = cols[(size_t)n * MAXE + tid];
    float xv = X[(size_t)n * FDIM + tid];
    float smean = 0.f;
#pragma unroll
    for (int hd = 0; hd < NHEAD; hd++) {
        __syncthreads();
        if (tid < MAXE) {
            float e;
            if (tid < c) {
                float z = fsrc[(hd << 12) + n] + fdst[(hd << 12) + cls[tid]];
                e = z > 0.f ? z : SLOPE * z;
            } else {
                e = -1e30f;
            }
            ev[tid] = e;
        }
        __syncthreads();
        if (tid < 64) {
            float m0 = fmaxf(ev[tid], ev[tid + 64]);
            for (int off = 32; off; off >>= 1) m0 = fmaxf(m0, __shfl_down(m0, off));
            m0 = __shfl(m0, 0);
            float e0 = (tid      < c) ? expf(ev[tid]      - m0) : 0.f;
            float e1 = (tid + 64 < c) ? expf(ev[tid + 64] - m0) : 0.f;
            ev[tid] = e0; ev[tid + 64] = e1;
            float s = e0 + e1;
            for (int off = 32; off; off >>= 1) s += __shfl_down(s, off);
            if (tid == 0) sinv_s = 1.f / s;
        }
        __syncthreads();
        const ushort* hh = h + (size_t)hd * NNODE * FDIM;
        float inv = sinv_s;
        float acc = 0.f;
        for (int j = 0; j < c; j++) {
            acc += ev[j] * bf2f(hh[(size_t)cls[j] * FDIM + tid]);   // 512B/edge gather
        }
        float v = acc * inv + xv;
        smean += v > 0.f ? v : expm1f(v);
    }
    float r = 0.25f * smean;
    Y[(size_t)n * FDIM + tid]   = r;
    Ybf[(size_t)n * FDIM + tid] = f2bf(r);
}

// ---------------- bf16 MFMA GEMM core (both operands [dim][K] row-major) ----
// Frag layouts: A: lane l holds A[l&15][8*(l>>4)+i]; B: B[8*(l>>4)+i][l&15]
// (= Bt row l&15); D: D[4*(l>>4)+ii][l&15] (m89 HW-verified).
// Any pure k-permutation error cancels (both operands loaded identically).
// BM=BN=128, BK=64, K=256 fixed. 4 waves, 64x64 per wave. Pad 72: 2-way (free).

// proj: Cbf[hd][4096][256] = Xbf @ WbfT[hd]^T
__global__ __launch_bounds__(256) void proj_mfma_k(const ushort* __restrict__ Abf,
                                                   const ushort* __restrict__ BtAll,
                                                   ushort* __restrict__ CbfAll) {
    __shared__ short As[128][72];
    __shared__ short Bs[128][72];
    const ushort* Bt = BtAll + (size_t)blockIdx.z * FDIM * FDIM;
    ushort* C = CbfAll + (size_t)blockIdx.z * NNODE * FDIM;
    int row0 = blockIdx.x * 128, col0 = blockIdx.y * 128;
    int t = threadIdx.x, lane = t & 63, w = t >> 6;
    int wm = (w >> 1) * 64, wn = (w & 1) * 64;
    int q = lane >> 4, cl = lane & 15;
    f32x4 acc[4][4];
#pragma unroll
    for (int i = 0; i < 4; i++)
#pragma unroll
        for (int j = 0; j < 4; j++) acc[i][j] = (f32x4)0.f;

    int sr = t >> 3, kc = (t & 7) * 8;
    for (int k0 = 0; k0 < FDIM; k0 += 64) {
        __syncthreads();
#pragma unroll
        for (int p = 0; p < 4; p++)
            *(bf16x8*)&As[p * 32 + sr][kc] = *(const bf16x8*)&Abf[(size_t)(row0 + p * 32 + sr) * FDIM + k0 + kc];
#pragma unroll
        for (int p = 0; p < 4; p++)
            *(bf16x8*)&Bs[p * 32 + sr][kc] = *(const bf16x8*)&Bt[(size_t)(col0 + p * 32 + sr) * FDIM + k0 + kc];
        __syncthreads();
#pragma unroll
        for (int kk = 0; kk < 2; kk++) {
            bf16x8 af[4], bfr[4];
#pragma unroll
            for (int i = 0; i < 4; i++) af[i]  = *(const bf16x8*)&As[wm + i * 16 + cl][kk * 32 + q * 8];
#pragma unroll
            for (int j = 0; j < 4; j++) bfr[j] = *(const bf16x8*)&Bs[wn + j * 16 + cl][kk * 32 + q * 8];
#pragma unroll
            for (int i = 0; i < 4; i++)
#pragma unroll
                for (int j = 0; j < 4; j++)
                    acc[i][j] = __builtin_amdgcn_mfma_f32_16x16x32_bf16(af[i], bfr[j], acc[i][j], 0, 0, 0);
        }
    }
#pragma unroll
    for (int i = 0; i < 4; i++)
#pragma unroll
        for (int j = 0; j < 4; j++)
#pragma unroll
            for (int ii = 0; ii < 4; ii++)
                C[(size_t)(row0 + wm + i * 16 + 4 * q + ii) * FDIM + col0 + wn + j * 16 + cl] =
                    f2bf(acc[i][j][ii]);
}

// syrk: out = Ybf @ Ybf^T (fp32 out), lower-tri blocks + bit-exact mirror
__global__ __launch_bounds__(256) void syrk_mfma_k(const ushort* __restrict__ Ybf,
                                                   float* __restrict__ out) {
    int bx = blockIdx.x, by = blockIdx.y;
    if (bx < by) return;
    __shared__ short As[128][72];
    __shared__ short Bs[128][72];
    int row0 = bx * 128, col0 = by * 128;
    int t = threadIdx.x, lane = t & 63, w = t >> 6;
    int wm = (w >> 1) * 64, wn = (w & 1) * 64;
    int q = lane >> 4, cl = lane & 15;
    f32x4 acc[4][4];
#pragma unroll
    for (int i = 0; i < 4; i++)
#pragma unroll
        for (int j = 0; j < 4; j++) acc[i][j] = (f32x4)0.f;

    int sr = t >> 3, kc = (t & 7) * 8;
    for (int k0 = 0; k0 < FDIM; k0 += 64) {
        __syncthreads();
#pragma unroll
        for (int p = 0; p < 4; p++)
            *(bf16x8*)&As[p * 32 + sr][kc] = *(const bf16x8*)&Ybf[(size_t)(row0 + p * 32 + sr) * FDIM + k0 + kc];
#pragma unroll
        for (int p = 0; p < 4; p++)
            *(bf16x8*)&Bs[p * 32 + sr][kc] = *(const bf16x8*)&Ybf[(size_t)(col0 + p * 32 + sr) * FDIM + k0 + kc];
        __syncthreads();
#pragma unroll
        for (int kk = 0; kk < 2; kk++) {
            bf16x8 af[4], bfr[4];
#pragma unroll
            for (int i = 0; i < 4; i++) af[i]  = *(const bf16x8*)&As[wm + i * 16 + cl][kk * 32 + q * 8];
#pragma unroll
            for (int j = 0; j < 4; j++) bfr[j] = *(const bf16x8*)&Bs[wn + j * 16 + cl][kk * 32 + q * 8];
#pragma unroll
            for (int i = 0; i < 4; i++)
#pragma unroll
                for (int j = 0; j < 4; j++)
                    acc[i][j] = __builtin_amdgcn_mfma_f32_16x16x32_bf16(af[i], bfr[j], acc[i][j], 0, 0, 0);
        }
    }
    // direct (lower) tile: lanes 0-15 give 64B coalesced chunks per (q,ii)
#pragma unroll
    for (int i = 0; i < 4; i++)
#pragma unroll
        for (int j = 0; j < 4; j++)
#pragma unroll
            for (int ii = 0; ii < 4; ii++)
                out[(size_t)(row0 + wm + i * 16 + 4 * q + ii) * NNODE + col0 + wn + j * 16 + cl] =
                    acc[i][j][ii];
    // mirror (upper): acc[i][j] is 4 consecutive rows at one col -> float4 row
    if (bx != by) {
#pragma unroll
        for (int i = 0; i < 4; i++)
#pragma unroll
            for (int j = 0; j < 4; j++)
                *(f32x4*)&out[(size_t)(col0 + wn + j * 16 + cl) * NNODE + row0 + wm + i * 16 + 4 * q] =
                    acc[i][j];
    }
}

extern "C" void kernel_launch(void* const* d_in, const int* in_sizes, int n_in,
                              void* d_out, int out_size, void* d_ws, size_t ws_size,
                              hipStream_t stream) {
    const float*         x   = (const float*)d_in[0];
    const unsigned char* adj = (const unsigned char*)d_in[1];   // layout auto-detected
    const float*         W   = (const float*)d_in[2];
    const float*         a   = (const float*)d_in[3];
    float*               out = (float*)d_out;

    // Scratch parked inside d_out (64 MB), all dead before syrk writes:
    ushort* hbf  = (ushort*)d_out;                               // [H,N,F] 8 MB
    ushort* xbf  = hbf + (size_t)NHEAD * NNODE * FDIM;           // [N,F] 2 MB
    ushort* WbfT = xbf + (size_t)NNODE * FDIM;                   // [H,F,F] 512 KB
    // d_ws ~14.2 MB:
    float* bufA   = (float*)d_ws;                                // [N,F] 4 MB
    float* bufB   = bufA + (size_t)NNODE * FDIM;                 // [N,F] 4 MB
    ushort* bufAbf = (ushort*)(bufB + (size_t)NNODE * FDIM);     // [N,F] 2 MB
    ushort* bufBbf = bufAbf + (size_t)NNODE * FDIM;              // [N,F] 2 MB
    float* fsrc = (float*)(bufBbf + (size_t)NNODE * FDIM);       // [H,N]
    float* fdst = fsrc + (size_t)NHEAD * NNODE;                  // [H,N]
    int*   cols = (int*)(fdst + (size_t)NHEAD * NNODE);          // [N,128] 2 MB
    int*   cnt  = cols + (size_t)NNODE * MAXE;                   // [N]
    int*   flag = cnt + NNODE;                                   // [1]

    detect_adj_k<<<1, 256, 0, stream>>>(adj, flag);
    build_edges_k<<<NNODE, 256, 0, stream>>>(adj, flag, cols, cnt);
    cast_x_k<<<NNODE * FDIM / 1024, 256, 0, stream>>>(x, xbf);
    cast_wT_k<<<NHEAD * FDIM, 256, 0, stream>>>(W, WbfT);

    auto layer = [&](const float* Xf, const ushort* Xbf, float* Yf, ushort* Ybf) {
        proj_mfma_k<<<dim3(32, 2, NHEAD), 256, 0, stream>>>(Xbf, WbfT, hbf);
        fvec_k<<<NHEAD * NNODE / 4, 256, 0, stream>>>(hbf, a, fsrc, fdst);
        agg_fused_k<<<NNODE, 256, 0, stream>>>(hbf, fsrc, fdst, cols, cnt, Xf, Yf, Ybf);
    };

    layer(x,    xbf,    bufA, bufAbf);
    layer(bufA, bufAbf, bufB, bufBbf);
    layer(bufB, bufBbf, bufA, bufAbf);

    syrk_mfma_k<<<dim3(32, 32, 1), 256, 0, stream>>>(bufAbf, out);
}